// Round 16
// baseline (753.410 us; speedup 1.0000x reference)
//
#include <hip/hip_runtime.h>

// KNN top-16: B=4, N=8192, D=16, k=16, fp32 in, int32 index out.
// FROZEN key model (validated R11-R15, absmax=0): harness np twin =
//   dot  = BLAS microkernel single-accumulator FMA chain, k = 0..15
//   norm = numpy AVX512 pairwise tree: r_j=m_j+m_{j+8}; q_j=r_j+r_{j+4};
//          fl(fl(q0+q2)+fl(q1+q3))
//   val  = fl( fl(ni + fl(-2*dot)) + nj ), ties -> lower index
// Keys are packed u64 = (mono32(fp32 key) << 32) | idx: u64 ascending ==
// (key asc, idx asc) == the frozen tie rule. Scan selection and refine rank
// use the SAME u64 order -> pool membership provably exact.
// R16: scan's reactive LDS-flush/insert (measured ~170 VALU/iter overhead)
// replaced by a fixed-cost register bitonic engine: batch 16 candidates ->
// sort16 (80 CE) -> min-pair vs sorted top16 (16) -> 4-stage cleanup (32 CE).
// Branch-free, no LDS, no divergence.

#define B_   4
#define N_   8192
#define D_   16
#define K_   16
#define BT_  128            // scan block threads (2 waves)
#define NQ_  (B_ * N_)      // 32768 queries

typedef unsigned long long u64;

// numpy AVX512 pairwise-sum tree for 16 contiguous floats. FROZEN.
__device__ __forceinline__ float np_norm16(const float* __restrict__ p) {
#pragma clang fp contract(off)
  float m[16];
#pragma unroll
  for (int d = 0; d < 16; ++d) m[d] = p[d] * p[d];
  float r[8];
#pragma unroll
  for (int j = 0; j < 8; ++j) r[j] = m[j] + m[j + 8];
  float q[4];
#pragma unroll
  for (int j = 0; j < 4; ++j) q[j] = r[j] + r[j + 4];
  return (q[0] + q[2]) + (q[1] + q[3]);
}

// monotone fp32->u32: uint ascending == float ascending (handles negatives)
__device__ __forceinline__ unsigned mono32(float f) {
  unsigned u = __float_as_uint(f);
  return u ^ ((unsigned)((int)u >> 31) | 0x80000000u);
}

__global__ __launch_bounds__(256) void knn_norms(const float* __restrict__ x,
                                                 float* __restrict__ nrm) {
  int q = blockIdx.x * 256 + threadIdx.x;
  float row[16];
  const float4* xv = (const float4*)(x + (size_t)q * D_);
  float4 a = xv[0], b = xv[1], c = xv[2], d = xv[3];
  row[0]=a.x; row[1]=a.y; row[2]=a.z; row[3]=a.w;
  row[4]=b.x; row[5]=b.y; row[6]=b.z; row[7]=b.w;
  row[8]=c.x; row[9]=c.y; row[10]=c.z; row[11]=c.w;
  row[12]=d.x; row[13]=d.y; row[14]=d.z; row[15]=d.w;
  nrm[q] = np_norm16(row);
}

template <int S, bool WRITE64>
__global__ __launch_bounds__(BT_) void knn_scan(const float* __restrict__ x,
                                                const float* __restrict__ nrm,
                                                void* __restrict__ pool) {
  constexpr int SEG = N_ / S;
  const int tid = threadIdx.x;
  const int q   = blockIdx.x * BT_ + tid;
  const int seg = blockIdx.y;
  // batch from blockIdx ONLY -> workgroup-uniform -> s_load staging.
  const int bq  = (int)((blockIdx.x * (unsigned)BT_) >> 13);
  const int row0 = bq * N_ + seg * SEG;
  const float* __restrict__ cbase = x + (size_t)row0 * D_;   // SGPR pointer
  const float* __restrict__ nbase = nrm + row0;              // SGPR pointer

  float qa[D_];
  {
    const float4* qv = (const float4*)(x + (size_t)q * D_);
    float4 v0 = qv[0], v1 = qv[1], v2 = qv[2], v3 = qv[3];
    qa[0]=v0.x; qa[1]=v0.y; qa[2]=v0.z; qa[3]=v0.w;
    qa[4]=v1.x; qa[5]=v1.y; qa[6]=v1.z; qa[7]=v1.w;
    qa[8]=v2.x; qa[9]=v2.y; qa[10]=v2.z; qa[11]=v2.w;
    qa[12]=v3.x; qa[13]=v3.y; qa[14]=v3.z; qa[15]=v3.w;
  }
  const float ni = nrm[q];

  u64 top[K_];               // sorted ascending; sentinel-initialized
#pragma unroll
  for (int p = 0; p < K_; ++p) top[p] = ~0ull;

#pragma unroll 1
  for (int t0 = 0; t0 < SEG; t0 += 16) {
    u64 ns[16];
    // collect 16 candidates: np-exact keys, packed
#pragma unroll
    for (int u = 0; u < 16; u += 2) {
      const int t = t0 + u;
      float dot0 = 0.f, dot1 = 0.f;
#pragma unroll
      for (int d = 0; d < D_; ++d) {
        dot0 = __builtin_fmaf(qa[d], cbase[(size_t)t * D_ + d], dot0);
        dot1 = __builtin_fmaf(qa[d], cbase[(size_t)(t + 1) * D_ + d], dot1);
      }
      float nj0 = nbase[t], nj1 = nbase[t + 1];
      float d0, d1;
      {
#pragma clang fp contract(off)
        float i0 = -2.0f * dot0;  float i1 = -2.0f * dot1;
        float u0 = ni + i0;       float u1 = ni + i1;
        d0 = u0 + nj0;            d1 = u1 + nj1;
      }
      ns[u]     = ((u64)mono32(d0) << 32) | (unsigned)(seg * SEG + t);
      ns[u + 1] = ((u64)mono32(d1) << 32) | (unsigned)(seg * SEG + t + 1);
    }

    // bitonic sort ns ascending (canonical network, compile-time unrolled)
#pragma unroll
    for (int k = 2; k <= 16; k <<= 1) {
#pragma unroll
      for (int j = k >> 1; j > 0; j >>= 1) {
#pragma unroll
        for (int i = 0; i < 16; ++i) {
          int l = i ^ j;
          if (l > i) {
            bool up = ((i & k) == 0);
            u64 a = ns[i], b = ns[l];
            bool sw = up ? (a > b) : (a < b);
            ns[i] = sw ? b : a;
            ns[l] = sw ? a : b;
          }
        }
      }
    }

    // 16 smallest of {top, ns}: first bitonic-merge stage of top ++ rev(ns)
#pragma unroll
    for (int i = 0; i < 16; ++i) {
      u64 a = top[i], b = ns[15 - i];
      top[i] = (b < a) ? b : a;      // lower half = 16 smallest, bitonic
    }
    // cleanup: bitonic merge to ascending (j = 8,4,2,1)
#pragma unroll
    for (int j = 8; j > 0; j >>= 1) {
#pragma unroll
      for (int i = 0; i < 16; ++i) {
        if ((i & j) == 0) {
          int l = i + j;
          u64 a = top[i], b = top[l];
          bool sw = a > b;
          top[i] = sw ? b : a;
          top[l] = sw ? a : b;
        }
      }
    }
  }

  if (WRITE64) {
    u64* pp = (u64*)pool + ((size_t)q * S + seg) * K_;
#pragma unroll
    for (int p = 0; p < K_; ++p) pp[p] = top[p];
  } else {
    unsigned* pp = (unsigned*)((unsigned short*)pool + ((size_t)q * S + seg) * K_);
#pragma unroll
    for (int p = 0; p < K_ / 2; ++p) {
      unsigned lo = (unsigned)(top[2 * p] & 0xffffu);
      unsigned hi = (unsigned)(top[2 * p + 1] & 0xffffu);
      pp[p] = lo | (hi << 16);
    }
  }
}

// u64-pool refine: pure rank of stored keys. u64 asc == (key asc, idx asc).
template <int S>
__global__ __launch_bounds__(256) void knn_refine64(const u64* __restrict__ pool,
                                                    int* __restrict__ out) {
  constexpr int POOL = S * K_;       // 128 or 256
  constexpr int SL   = POOL / 64;    // 2 or 4 slots per lane
  const int tid  = threadIdx.x;
  const int lane = tid & 63;
  const int q    = blockIdx.x * 4 + (tid >> 6);  // one wave per query
  const u64* __restrict__ pp = pool + (size_t)q * POOL;

  u64 e[SL];
#pragma unroll
  for (int s = 0; s < SL; ++s) e[s] = pp[lane + 64 * s];

  int rr[SL];
#pragma unroll
  for (int s = 0; s < SL; ++s) rr[s] = 0;
  for (int t = 0; t < 64; ++t) {
#pragma unroll
    for (int a = 0; a < SL; ++a) {
      u64 ea = __shfl(e[a], t);
#pragma unroll
      for (int s = 0; s < SL; ++s) rr[s] += (ea < e[s]) ? 1 : 0;
    }
  }
#pragma unroll
  for (int s = 0; s < SL; ++s)
    if (rr[s] < K_) out[(size_t)q * K_ + rr[s]] = (int)(e[s] & 0xffffu);
}

// Fallback refine (u16 idx pool): recompute np-exact key (R13/R14-proven).
__device__ __forceinline__ float np_adj1(const float* __restrict__ qa,
                                         const float* __restrict__ cj,
                                         float ni, float nj) {
  float dot = 0.f;
#pragma unroll
  for (int d = 0; d < 16; ++d) dot = __builtin_fmaf(qa[d], cj[d], dot);
  float val;
  {
#pragma clang fp contract(off)
    float inner = -2.0f * dot;
    float u = ni + inner;
    val = u + nj;
  }
  return val;
}

template <int S>
__global__ __launch_bounds__(256) void knn_refine16(const float* __restrict__ x,
                                                    const float* __restrict__ nrm,
                                                    const unsigned short* __restrict__ pool,
                                                    int* __restrict__ out) {
  constexpr int POOL = S * K_;
  constexpr int SL   = POOL / 64;
  const int tid  = threadIdx.x;
  const int lane = tid & 63;
  const int q    = blockIdx.x * 4 + (tid >> 6);
  const int b    = q >> 13;
  const unsigned short* __restrict__ pp = pool + (size_t)q * POOL;

  float qa[D_];
  {
    const float4* qv = (const float4*)(x + (size_t)q * D_);
    float4 v0 = qv[0], v1 = qv[1], v2 = qv[2], v3 = qv[3];
    qa[0]=v0.x; qa[1]=v0.y; qa[2]=v0.z; qa[3]=v0.w;
    qa[4]=v1.x; qa[5]=v1.y; qa[6]=v1.z; qa[7]=v1.w;
    qa[8]=v2.x; qa[9]=v2.y; qa[10]=v2.z; qa[11]=v2.w;
    qa[12]=v3.x; qa[13]=v3.y; qa[14]=v3.z; qa[15]=v3.w;
  }
  const float ni = nrm[q];

  int   jj[SL];
  float vv[SL];
#pragma unroll
  for (int s = 0; s < SL; ++s) {
    int j = (int)pp[lane + 64 * s];
    jj[s] = j;
    float cj[D_];
    const float4* cv = (const float4*)(x + ((size_t)(b * N_) + j) * D_);
    float4 a = cv[0], bb = cv[1], c = cv[2], d = cv[3];
    cj[0]=a.x; cj[1]=a.y; cj[2]=a.z; cj[3]=a.w;
    cj[4]=bb.x; cj[5]=bb.y; cj[6]=bb.z; cj[7]=bb.w;
    cj[8]=c.x; cj[9]=c.y; cj[10]=c.z; cj[11]=c.w;
    cj[12]=d.x; cj[13]=d.y; cj[14]=d.z; cj[15]=d.w;
    vv[s] = np_adj1(qa, cj, ni, nrm[b * N_ + j]);
  }
  int rr[SL];
#pragma unroll
  for (int s = 0; s < SL; ++s) rr[s] = 0;
  for (int t = 0; t < 64; ++t) {
#pragma unroll
    for (int a = 0; a < SL; ++a) {
      float va = __shfl(vv[a], t);
      int   ja = __shfl(jj[a], t);
#pragma unroll
      for (int s = 0; s < SL; ++s)
        rr[s] += (va < vv[s] || (va == vv[s] && ja < jj[s])) ? 1 : 0;
    }
  }
#pragma unroll
  for (int s = 0; s < SL; ++s)
    if (rr[s] < K_) out[(size_t)q * K_ + rr[s]] = jj[s];
}

extern "C" void kernel_launch(void* const* d_in, const int* in_sizes, int n_in,
                              void* d_out, int out_size, void* d_ws, size_t ws_size,
                              hipStream_t stream) {
  const float* x = (const float*)d_in[0];
  float* nrm = (float*)d_ws;                         // 128 KB used of 256 KB
  void* pool = (void*)((char*)d_ws + 256 * 1024);
  int* out = (int*)d_out;

  knn_norms<<<NQ_ / 256, 256, 0, stream>>>(x, nrm);

  const size_t base = 256 * 1024;
  const size_t need16_64 = base + (size_t)NQ_ * 16 * K_ * 8;  // 64.25 MB
  const size_t need8_64  = base + (size_t)NQ_ * 8  * K_ * 8;  // 32.25 MB

  if (ws_size >= need16_64) {
    dim3 g2(NQ_ / BT_, 16);
    knn_scan<16, true><<<g2, BT_, 0, stream>>>(x, nrm, pool);
    knn_refine64<16><<<NQ_ / 4, 256, 0, stream>>>((const u64*)pool, out);
  } else if (ws_size >= need8_64) {
    dim3 g2(NQ_ / BT_, 8);
    knn_scan<8, true><<<g2, BT_, 0, stream>>>(x, nrm, pool);
    knn_refine64<8><<<NQ_ / 4, 256, 0, stream>>>((const u64*)pool, out);
  } else {
    dim3 g2(NQ_ / BT_, 8);
    knn_scan<8, false><<<g2, BT_, 0, stream>>>(x, nrm, pool);
    knn_refine16<8><<<NQ_ / 4, 256, 0, stream>>>(x, nrm,
                                                 (const unsigned short*)pool, out);
  }
}

// Round 17
// 562.719 us; speedup vs baseline: 1.3389x; 1.3389x over previous
//
#include <hip/hip_runtime.h>

// KNN top-16: B=4, N=8192, D=16, k=16, fp32 in, int32 index out.
// FROZEN key model (validated R11-R16, absmax=0): harness np twin =
//   dot  = BLAS microkernel single-accumulator FMA chain, k = 0..15
//   norm = numpy AVX512 pairwise tree: r_j=m_j+m_{j+8}; q_j=r_j+r_{j+4};
//          fl(fl(q0+q2)+fl(q1+q3))
//   val  = fl( fl(ni + fl(-2*dot)) + nj ), ties -> lower index
// Keys packed u64 = (mono32(key)<<32)|idx: u64 asc == (key asc, idx asc).
// R17: revert scan to R15's LDS-flush structure (bitonic R16 regressed:
// unconditional 128-CE network > data-dependent flush cost). S=8 everywhere:
// scan equal-cost vs S=16 (455 vs 452 measured), refine64 SL=2 is ~4x
// cheaper than SL=4 (~95us -> ~17us). Pool 32MB.

#define B_   4
#define N_   8192
#define D_   16
#define K_   16
#define BT_  128            // scan block threads (2 waves)
#define CAP_ 8              // per-lane LDS append buffer capacity
#define NQ_  (B_ * N_)      // 32768 queries

typedef unsigned long long u64;

// numpy AVX512 pairwise-sum tree for 16 contiguous floats. FROZEN.
__device__ __forceinline__ float np_norm16(const float* __restrict__ p) {
#pragma clang fp contract(off)
  float m[16];
#pragma unroll
  for (int d = 0; d < 16; ++d) m[d] = p[d] * p[d];
  float r[8];
#pragma unroll
  for (int j = 0; j < 8; ++j) r[j] = m[j] + m[j + 8];
  float q[4];
#pragma unroll
  for (int j = 0; j < 4; ++j) q[j] = r[j] + r[j + 4];
  return (q[0] + q[2]) + (q[1] + q[3]);
}

// monotone fp32->u32: uint ascending == float ascending (handles negatives)
__device__ __forceinline__ unsigned mono32(float f) {
  unsigned u = __float_as_uint(f);
  return u ^ ((unsigned)((int)u >> 31) | 0x80000000u);
}

__global__ __launch_bounds__(256) void knn_norms(const float* __restrict__ x,
                                                 float* __restrict__ nrm) {
  int q = blockIdx.x * 256 + threadIdx.x;
  float row[16];
  const float4* xv = (const float4*)(x + (size_t)q * D_);
  float4 a = xv[0], b = xv[1], c = xv[2], d = xv[3];
  row[0]=a.x; row[1]=a.y; row[2]=a.z; row[3]=a.w;
  row[4]=b.x; row[5]=b.y; row[6]=b.z; row[7]=b.w;
  row[8]=c.x; row[9]=c.y; row[10]=c.z; row[11]=c.w;
  row[12]=d.x; row[13]=d.y; row[14]=d.z; row[15]=d.w;
  nrm[q] = np_norm16(row);
}

// ascending insert; '>' keeps earlier (lower idx) on ties
__device__ __forceinline__ void insert16(float d, int j, float (&kd)[K_], int (&ki)[K_]) {
  float cd = d; int ci = j;
#pragma unroll
  for (int p = 0; p < K_; ++p) {
    bool gt = kd[p] > cd;
    float t0 = gt ? cd : kd[p];
    float t1 = gt ? kd[p] : cd;
    int   t2 = gt ? ci : ki[p];
    int   t3 = gt ? ki[p] : ci;
    kd[p] = t0; cd = t1; ki[p] = t2; ci = t3;
  }
}

__device__ __forceinline__ void flushbuf(u64 (*buf)[BT_], int tid,
                                         int& count, float& thr,
                                         float (&kd)[K_], int (&ki)[K_]) {
#pragma unroll 1
  for (int s = 0; s < CAP_; ++s) {
    if (s < count) {
      u64 e = buf[s][tid];
      float d = __uint_as_float((unsigned)(e >> 32));
      if (d < thr) {
        int j = (int)(e & 0xffffu);
        insert16(d, j, kd, ki);
        thr = kd[K_ - 1];
      }
    }
  }
  count = 0;
}

// Scan: per-(query,segment) np-exact top-16; writes u64 (mono key | idx)
// or u16 idx (fallback).
template <int S, bool WRITE64>
__global__ __launch_bounds__(BT_) void knn_scan(const float* __restrict__ x,
                                                const float* __restrict__ nrm,
                                                void* __restrict__ pool) {
  constexpr int SEG = N_ / S;
  __shared__ u64 buf[CAP_][BT_];
  const int tid = threadIdx.x;
  const int q   = blockIdx.x * BT_ + tid;
  const int seg = blockIdx.y;
  // batch from blockIdx ONLY -> workgroup-uniform -> s_load staging.
  const int bq  = (int)((blockIdx.x * (unsigned)BT_) >> 13);
  const int row0 = bq * N_ + seg * SEG;
  const float* __restrict__ cbase = x + (size_t)row0 * D_;   // SGPR pointer
  const float* __restrict__ nbase = nrm + row0;              // SGPR pointer

  float qa[D_];
  {
    const float4* qv = (const float4*)(x + (size_t)q * D_);
    float4 v0 = qv[0], v1 = qv[1], v2 = qv[2], v3 = qv[3];
    qa[0]=v0.x; qa[1]=v0.y; qa[2]=v0.z; qa[3]=v0.w;
    qa[4]=v1.x; qa[5]=v1.y; qa[6]=v1.z; qa[7]=v1.w;
    qa[8]=v2.x; qa[9]=v2.y; qa[10]=v2.z; qa[11]=v2.w;
    qa[12]=v3.x; qa[13]=v3.y; qa[14]=v3.z; qa[15]=v3.w;
  }
  const float ni = nrm[q];

  float kd[K_]; int ki[K_];
#pragma unroll
  for (int p = 0; p < K_; ++p) { kd[p] = 3.4e38f; ki[p] = 0; }
  float thr = 3.4e38f;
  int count = 0;

#pragma unroll 1
  for (int t = 0; t < SEG; t += 2) {
    float c0[D_], c1[D_];
#pragma unroll
    for (int d = 0; d < D_; ++d) c0[d] = cbase[(size_t)t * D_ + d];
#pragma unroll
    for (int d = 0; d < D_; ++d) c1[d] = cbase[(size_t)(t + 1) * D_ + d];
    float nj0 = nbase[t];
    float nj1 = nbase[t + 1];

    // two independent np-exact FMA chains, interleaved
    float dot0 = 0.f, dot1 = 0.f;
#pragma unroll
    for (int d = 0; d < D_; ++d) {
      dot0 = __builtin_fmaf(qa[d], c0[d], dot0);
      dot1 = __builtin_fmaf(qa[d], c1[d], dot1);
    }
    float d0, d1;
    {
#pragma clang fp contract(off)
      float i0 = -2.0f * dot0;  float i1 = -2.0f * dot1;
      float u0 = ni + i0;       float u1 = ni + i1;
      d0 = u0 + nj0;            d1 = u1 + nj1;
    }

    if (d0 < thr) {
      buf[count][tid] = ((u64)__float_as_uint(d0) << 32) | (unsigned)t;
      ++count;
    }
    if (d1 < thr) {
      buf[count][tid] = ((u64)__float_as_uint(d1) << 32) | (unsigned)(t + 1);
      ++count;
    }
    if (__any(count >= CAP_ - 1)) flushbuf(buf, tid, count, thr, kd, ki);
  }
  flushbuf(buf, tid, count, thr, kd, ki);

  if (WRITE64) {
    u64* pp = (u64*)pool + ((size_t)q * S + seg) * K_;
#pragma unroll
    for (int p = 0; p < K_; ++p) {
      unsigned gj = (unsigned)(seg * SEG + ki[p]);
      pp[p] = ((u64)mono32(kd[p]) << 32) | gj;
    }
  } else {
    unsigned* pp = (unsigned*)((unsigned short*)pool + ((size_t)q * S + seg) * K_);
#pragma unroll
    for (int p = 0; p < K_ / 2; ++p) {
      unsigned lo = (unsigned)(ki[2 * p] + seg * SEG);
      unsigned hi = (unsigned)(ki[2 * p + 1] + seg * SEG);
      pp[p] = lo | (hi << 16);
    }
  }
}

// u64-pool refine: pure rank of stored keys. u64 asc == (key asc, idx asc).
template <int S>
__global__ __launch_bounds__(256) void knn_refine64(const u64* __restrict__ pool,
                                                    int* __restrict__ out) {
  constexpr int POOL = S * K_;       // 128
  constexpr int SL   = POOL / 64;    // 2 slots per lane
  const int tid  = threadIdx.x;
  const int lane = tid & 63;
  const int q    = blockIdx.x * 4 + (tid >> 6);  // one wave per query
  const u64* __restrict__ pp = pool + (size_t)q * POOL;

  u64 e[SL];
#pragma unroll
  for (int s = 0; s < SL; ++s) e[s] = pp[lane + 64 * s];

  int rr[SL];
#pragma unroll
  for (int s = 0; s < SL; ++s) rr[s] = 0;
  for (int t = 0; t < 64; ++t) {
#pragma unroll
    for (int a = 0; a < SL; ++a) {
      u64 ea = __shfl(e[a], t);
#pragma unroll
      for (int s = 0; s < SL; ++s) rr[s] += (ea < e[s]) ? 1 : 0;
    }
  }
#pragma unroll
  for (int s = 0; s < SL; ++s)
    if (rr[s] < K_) out[(size_t)q * K_ + rr[s]] = (int)(e[s] & 0xffffu);
}

// Fallback refine (u16 idx pool): recompute np-exact key (R13-proven).
__device__ __forceinline__ float np_adj1(const float* __restrict__ qa,
                                         const float* __restrict__ cj,
                                         float ni, float nj) {
  float dot = 0.f;
#pragma unroll
  for (int d = 0; d < 16; ++d) dot = __builtin_fmaf(qa[d], cj[d], dot);
  float val;
  {
#pragma clang fp contract(off)
    float inner = -2.0f * dot;
    float u = ni + inner;
    val = u + nj;
  }
  return val;
}

template <int S>
__global__ __launch_bounds__(256) void knn_refine16(const float* __restrict__ x,
                                                    const float* __restrict__ nrm,
                                                    const unsigned short* __restrict__ pool,
                                                    int* __restrict__ out) {
  constexpr int POOL = S * K_;
  constexpr int SL   = POOL / 64;
  const int tid  = threadIdx.x;
  const int lane = tid & 63;
  const int q    = blockIdx.x * 4 + (tid >> 6);
  const int b    = q >> 13;
  const unsigned short* __restrict__ pp = pool + (size_t)q * POOL;

  float qa[D_];
  {
    const float4* qv = (const float4*)(x + (size_t)q * D_);
    float4 v0 = qv[0], v1 = qv[1], v2 = qv[2], v3 = qv[3];
    qa[0]=v0.x; qa[1]=v0.y; qa[2]=v0.z; qa[3]=v0.w;
    qa[4]=v1.x; qa[5]=v1.y; qa[6]=v1.z; qa[7]=v1.w;
    qa[8]=v2.x; qa[9]=v2.y; qa[10]=v2.z; qa[11]=v2.w;
    qa[12]=v3.x; qa[13]=v3.y; qa[14]=v3.z; qa[15]=v3.w;
  }
  const float ni = nrm[q];

  int   jj[SL];
  float vv[SL];
#pragma unroll
  for (int s = 0; s < SL; ++s) {
    int j = (int)pp[lane + 64 * s];
    jj[s] = j;
    float cj[D_];
    const float4* cv = (const float4*)(x + ((size_t)(b * N_) + j) * D_);
    float4 a = cv[0], bb = cv[1], c = cv[2], d = cv[3];
    cj[0]=a.x; cj[1]=a.y; cj[2]=a.z; cj[3]=a.w;
    cj[4]=bb.x; cj[5]=bb.y; cj[6]=bb.z; cj[7]=bb.w;
    cj[8]=c.x; cj[9]=c.y; cj[10]=c.z; cj[11]=c.w;
    cj[12]=d.x; cj[13]=d.y; cj[14]=d.z; cj[15]=d.w;
    vv[s] = np_adj1(qa, cj, ni, nrm[b * N_ + j]);
  }
  int rr[SL];
#pragma unroll
  for (int s = 0; s < SL; ++s) rr[s] = 0;
  for (int t = 0; t < 64; ++t) {
#pragma unroll
    for (int a = 0; a < SL; ++a) {
      float va = __shfl(vv[a], t);
      int   ja = __shfl(jj[a], t);
#pragma unroll
      for (int s = 0; s < SL; ++s)
        rr[s] += (va < vv[s] || (va == vv[s] && ja < jj[s])) ? 1 : 0;
    }
  }
#pragma unroll
  for (int s = 0; s < SL; ++s)
    if (rr[s] < K_) out[(size_t)q * K_ + rr[s]] = jj[s];
}

extern "C" void kernel_launch(void* const* d_in, const int* in_sizes, int n_in,
                              void* d_out, int out_size, void* d_ws, size_t ws_size,
                              hipStream_t stream) {
  const float* x = (const float*)d_in[0];
  float* nrm = (float*)d_ws;                         // 128 KB used of 256 KB
  void* pool = (void*)((char*)d_ws + 256 * 1024);
  int* out = (int*)d_out;

  knn_norms<<<NQ_ / 256, 256, 0, stream>>>(x, nrm);

  const size_t base = 256 * 1024;
  const size_t need8_64 = base + (size_t)NQ_ * 8 * K_ * 8;  // 32.25 MB

  if (ws_size >= need8_64) {
    dim3 g2(NQ_ / BT_, 8);
    knn_scan<8, true><<<g2, BT_, 0, stream>>>(x, nrm, pool);
    knn_refine64<8><<<NQ_ / 4, 256, 0, stream>>>((const u64*)pool, out);
  } else {
    dim3 g2(NQ_ / BT_, 8);
    knn_scan<8, false><<<g2, BT_, 0, stream>>>(x, nrm, pool);
    knn_refine16<8><<<NQ_ / 4, 256, 0, stream>>>(x, nrm,
                                                 (const unsigned short*)pool, out);
  }
}

// Round 18
// 426.955 us; speedup vs baseline: 1.7646x; 1.3180x over previous
//
#include <hip/hip_runtime.h>

// KNN top-16: B=4, N=8192, D=16, k=16, fp32 in, int32 index out.
// FROZEN key model (validated R11-R17, absmax=0): harness np twin =
//   dot  = BLAS microkernel single-accumulator FMA chain, k = 0..15
//   norm = numpy AVX512 pairwise tree: r_j=m_j+m_{j+8}; q_j=r_j+r_{j+4};
//          fl(fl(q0+q2)+fl(q1+q3))
//   val  = fl( fl(ni + fl(-2*dot)) + nj ), ties -> lower index
// Keys packed u64 = (mono32(key)<<32)|idx: u64 asc == (key asc, idx asc).
// R18: single fused kernel. Block = 512 thr = 8 waves = the 8 segments of 64
// queries (lane = query). Each wave double-buffers its segment through
// per-wave-private LDS (32-row chunks, coalesced float4 global loads, LDS
// broadcast reads) -> removes the s_load latency chain R17 stalled on.
// End: per-wave sorted top-16 u64 -> LDS [seg][p][query] -> in-block 8-way
// merge (8 lanes/query, shfl-xor min, 16 rounds) -> direct output. No pool,
// no refine kernel, no inter-kernel gaps.

#define B_    4
#define N_    8192
#define D_    16
#define K_    16
#define SEGS_ 8
#define SEG_  (N_ / SEGS_)   // 1024
#define CH_   32             // rows per staged chunk
#define NCH_  (SEG_ / CH_)   // 32 chunks
#define BT_   512            // 8 waves
#define CAP_  4              // per-lane LDS push-buffer capacity
#define NQ_   (B_ * N_)      // 32768 queries

typedef unsigned long long u64;

// numpy AVX512 pairwise-sum tree for 16 contiguous floats. FROZEN.
__device__ __forceinline__ float np_norm16(const float* __restrict__ p) {
#pragma clang fp contract(off)
  float m[16];
#pragma unroll
  for (int d = 0; d < 16; ++d) m[d] = p[d] * p[d];
  float r[8];
#pragma unroll
  for (int j = 0; j < 8; ++j) r[j] = m[j] + m[j + 8];
  float q[4];
#pragma unroll
  for (int j = 0; j < 4; ++j) q[j] = r[j] + r[j + 4];
  return (q[0] + q[2]) + (q[1] + q[3]);
}

// monotone fp32->u32: uint ascending == float ascending (handles negatives)
__device__ __forceinline__ unsigned mono32(float f) {
  unsigned u = __float_as_uint(f);
  return u ^ ((unsigned)((int)u >> 31) | 0x80000000u);
}

__global__ __launch_bounds__(256) void knn_norms(const float* __restrict__ x,
                                                 float* __restrict__ nrm) {
  int q = blockIdx.x * 256 + threadIdx.x;
  float row[16];
  const float4* xv = (const float4*)(x + (size_t)q * D_);
  float4 a = xv[0], b = xv[1], c = xv[2], d = xv[3];
  row[0]=a.x; row[1]=a.y; row[2]=a.z; row[3]=a.w;
  row[4]=b.x; row[5]=b.y; row[6]=b.z; row[7]=b.w;
  row[8]=c.x; row[9]=c.y; row[10]=c.z; row[11]=c.w;
  row[12]=d.x; row[13]=d.y; row[14]=d.z; row[15]=d.w;
  nrm[q] = np_norm16(row);
}

// ascending insert; '>' keeps earlier (lower idx) on ties
__device__ __forceinline__ void insert16(float d, int j, float (&kd)[K_], int (&ki)[K_]) {
  float cd = d; int ci = j;
#pragma unroll
  for (int p = 0; p < K_; ++p) {
    bool gt = kd[p] > cd;
    float t0 = gt ? cd : kd[p];
    float t1 = gt ? kd[p] : cd;
    int   t2 = gt ? ci : ki[p];
    int   t3 = gt ? ki[p] : ci;
    kd[p] = t0; cd = t1; ki[p] = t2; ci = t3;
  }
}

__device__ __forceinline__ void flushbuf(u64* __restrict__ pbuf, int tid,
                                         int& count, float& thr,
                                         float (&kd)[K_], int (&ki)[K_]) {
#pragma unroll 1
  for (int s = 0; s < CAP_; ++s) {
    if (s < count) {
      u64 e = pbuf[(size_t)s * BT_ + tid];
      float d = __uint_as_float((unsigned)(e >> 32));
      if (d < thr) {
        int j = (int)(e & 0xffffu);
        insert16(d, j, kd, ki);
        thr = kd[K_ - 1];
      }
    }
  }
  count = 0;
}

__global__ __launch_bounds__(BT_, 4) void knn_fused(const float* __restrict__ x,
                                                    const float* __restrict__ nrm,
                                                    int* __restrict__ out) {
  __shared__ u64 smem[8192];                       // 64 KB
  float4* stageR = (float4*)smem;                  // [ (w*2+b)*128 + i ]  0..32KB
  float*  stageN = (float*)(smem + 4096);          // [ (w*2+b)*32 + i ]  32..34KB
  u64*    pbuf   = smem + 4352;                    // [ s*512 + tid ]     34..50KB
  // merge overlay (after __syncthreads): smem[(seg*16+p)*64 + qlocal]  0..64KB

  const int tid  = threadIdx.x;
  const int w    = tid >> 6;                       // wave id = segment
  const int lane = tid & 63;                       // query-local id
  const int q    = blockIdx.x * 64 + lane;         // global query
  const int bq   = (int)((blockIdx.x * 64u) >> 13);  // batch (block-uniform)
  const int row0 = bq * N_ + w * SEG_;
  const float* __restrict__ cbase = x + (size_t)row0 * D_;
  const float* __restrict__ nbase = nrm + row0;

  float qa[D_];
  {
    const float4* qv = (const float4*)(x + (size_t)q * D_);
    float4 v0 = qv[0], v1 = qv[1], v2 = qv[2], v3 = qv[3];
    qa[0]=v0.x; qa[1]=v0.y; qa[2]=v0.z; qa[3]=v0.w;
    qa[4]=v1.x; qa[5]=v1.y; qa[6]=v1.z; qa[7]=v1.w;
    qa[8]=v2.x; qa[9]=v2.y; qa[10]=v2.z; qa[11]=v2.w;
    qa[12]=v3.x; qa[13]=v3.y; qa[14]=v3.z; qa[15]=v3.w;
  }
  const float ni = nrm[q];

  float kd[K_]; int ki[K_];
#pragma unroll
  for (int p = 0; p < K_; ++p) { kd[p] = 3.4e38f; ki[p] = 0; }
  float thr = 3.4e38f;
  int count = 0;

  // stage chunk 0 (per-wave-private LDS region; wave-synchronous, no barrier)
  {
    const float4* gs = (const float4*)cbase;
    stageR[(w * 2 + 0) * 128 + lane]      = gs[lane];
    stageR[(w * 2 + 0) * 128 + lane + 64] = gs[lane + 64];
    if (lane < CH_) stageN[(w * 2 + 0) * CH_ + lane] = nbase[lane];
  }

#pragma unroll 1
  for (int c = 0; c < NCH_; ++c) {
    const int b = c & 1;
    // prefetch chunk c+1 into registers (global loads overlap compute below)
    float4 p0, p1; float pn = 0.f;
    const bool more = (c + 1 < NCH_);
    if (more) {
      const float4* gs = (const float4*)(cbase + (size_t)(c + 1) * CH_ * D_);
      p0 = gs[lane];
      p1 = gs[lane + 64];
      if (lane < CH_) pn = nbase[(c + 1) * CH_ + lane];
    }

    const float4* rows = stageR + (w * 2 + b) * 128;
    const float*  nn   = stageN + (w * 2 + b) * CH_;

#pragma unroll 1
    for (int t = 0; t < CH_; t += 2) {
      float4 r00 = rows[t*4+0], r01 = rows[t*4+1], r02 = rows[t*4+2], r03 = rows[t*4+3];
      float4 r10 = rows[t*4+4], r11 = rows[t*4+5], r12 = rows[t*4+6], r13 = rows[t*4+7];
      float nj0 = nn[t], nj1 = nn[t + 1];

      float c0[16] = {r00.x,r00.y,r00.z,r00.w, r01.x,r01.y,r01.z,r01.w,
                      r02.x,r02.y,r02.z,r02.w, r03.x,r03.y,r03.z,r03.w};
      float c1[16] = {r10.x,r10.y,r10.z,r10.w, r11.x,r11.y,r11.z,r11.w,
                      r12.x,r12.y,r12.z,r12.w, r13.x,r13.y,r13.z,r13.w};

      // two independent np-exact FMA chains (k ascending, single accumulator)
      float dot0 = 0.f, dot1 = 0.f;
#pragma unroll
      for (int d = 0; d < D_; ++d) {
        dot0 = __builtin_fmaf(qa[d], c0[d], dot0);
        dot1 = __builtin_fmaf(qa[d], c1[d], dot1);
      }
      float d0, d1;
      {
#pragma clang fp contract(off)
        float i0 = -2.0f * dot0;  float i1 = -2.0f * dot1;
        float u0 = ni + i0;       float u1 = ni + i1;
        d0 = u0 + nj0;            d1 = u1 + nj1;
      }

      if (d0 < thr) {
        pbuf[(size_t)count * BT_ + tid] =
            ((u64)__float_as_uint(d0) << 32) | (unsigned)(c * CH_ + t);
        ++count;
      }
      if (d1 < thr) {
        pbuf[(size_t)count * BT_ + tid] =
            ((u64)__float_as_uint(d1) << 32) | (unsigned)(c * CH_ + t + 1);
        ++count;
      }
      if (__any(count >= CAP_ - 1)) flushbuf(pbuf, tid, count, thr, kd, ki);
    }

    // write prefetched chunk into the other buffer (waits vm for p0/p1)
    if (more) {
      stageR[(w * 2 + (b ^ 1)) * 128 + lane]      = p0;
      stageR[(w * 2 + (b ^ 1)) * 128 + lane + 64] = p1;
      if (lane < CH_) stageN[(w * 2 + (b ^ 1)) * CH_ + lane] = pn;
    }
  }
  flushbuf(pbuf, tid, count, thr, kd, ki);

  // ---- publish sorted per-segment top-16 as packed u64, then 8-way merge ----
  __syncthreads();   // all waves done with stage/push regions before overlay
#pragma unroll
  for (int p = 0; p < K_; ++p) {
    smem[((size_t)w * 16 + p) * 64 + lane] =
        ((u64)mono32(kd[p]) << 32) | (unsigned)(w * SEG_ + ki[p]);
  }
  __syncthreads();

  // merge: 8 lanes per query, one query-group per 8 lanes; wave w handles
  // queries [w*8, w*8+8). Keys are globally distinct (distinct idx).
  {
    const int qi = w * 8 + (lane >> 3);            // block-local query
    const int s  = lane & 7;                       // my segment stream
    const int gq = blockIdx.x * 64 + qi;           // global query
    int ptr = 0;
#pragma unroll 1
    for (int r = 0; r < K_; ++r) {
      u64 h = smem[((size_t)s * 16 + ptr) * 64 + qi];
      u64 m = h, o;
      o = __shfl_xor(m, 1); m = (o < m) ? o : m;
      o = __shfl_xor(m, 2); m = (o < m) ? o : m;
      o = __shfl_xor(m, 4); m = (o < m) ? o : m;
      if (h == m) ++ptr;                           // exactly one lane advances
      if (s == 0) out[(size_t)gq * K_ + r] = (int)(m & 0xffffu);
    }
  }
}

extern "C" void kernel_launch(void* const* d_in, const int* in_sizes, int n_in,
                              void* d_out, int out_size, void* d_ws, size_t ws_size,
                              hipStream_t stream) {
  const float* x = (const float*)d_in[0];
  float* nrm = (float*)d_ws;                       // 128 KB of workspace
  int* out = (int*)d_out;

  knn_norms<<<NQ_ / 256, 256, 0, stream>>>(x, nrm);
  knn_fused<<<NQ_ / 64, BT_, 0, stream>>>(x, nrm, out);
}

// Round 19
// 377.728 us; speedup vs baseline: 1.9946x; 1.1303x over previous
//
#include <hip/hip_runtime.h>

// KNN top-16: B=4, N=8192, D=16, k=16, fp32 in, int32 index out.
// FROZEN key model (validated R11-R18, absmax=0): harness np twin =
//   dot  = BLAS microkernel single-accumulator FMA chain, k = 0..15
//   norm = numpy AVX512 pairwise tree: r_j=m_j+m_{j+8}; q_j=r_j+r_{j+4};
//          fl(fl(q0+q2)+fl(q1+q3))
//   val  = fl( fl(ni + fl(-2*dot)) + nj ), ties -> lower index
// Keys packed u64 = (mono32(key)<<32)|idx: u64 asc == (key asc, idx asc).
// R19: CAP 4->12. R18 counters: 109 VALU/candidate, ~80 of it exec-masked
// insert16 from flushes firing every ~2 iters at ~15% lane efficiency.
// Large CAP batches pushes -> ~8 flushes/segment, insert16 issues ~88 vs
// ~300 (near the max-lane-pushes lower bound). Stage chunk 8 rows (LDS
// budget: stage 8.5KB + pbuf 48KB = 56.5KB; merge overlay 64KB).

#define B_    4
#define N_    8192
#define D_    16
#define K_    16
#define SEGS_ 8
#define SEG_  (N_ / SEGS_)   // 1024
#define CH_   8              // rows per staged chunk
#define NCH_  (SEG_ / CH_)   // 128 chunks
#define BT_   512            // 8 waves
#define CAP_  12             // per-lane LDS push-buffer capacity
#define NQ_   (B_ * N_)      // 32768 queries

typedef unsigned long long u64;

// numpy AVX512 pairwise-sum tree for 16 contiguous floats. FROZEN.
__device__ __forceinline__ float np_norm16(const float* __restrict__ p) {
#pragma clang fp contract(off)
  float m[16];
#pragma unroll
  for (int d = 0; d < 16; ++d) m[d] = p[d] * p[d];
  float r[8];
#pragma unroll
  for (int j = 0; j < 8; ++j) r[j] = m[j] + m[j + 8];
  float q[4];
#pragma unroll
  for (int j = 0; j < 4; ++j) q[j] = r[j] + r[j + 4];
  return (q[0] + q[2]) + (q[1] + q[3]);
}

// monotone fp32->u32: uint ascending == float ascending (handles negatives)
__device__ __forceinline__ unsigned mono32(float f) {
  unsigned u = __float_as_uint(f);
  return u ^ ((unsigned)((int)u >> 31) | 0x80000000u);
}

__global__ __launch_bounds__(256) void knn_norms(const float* __restrict__ x,
                                                 float* __restrict__ nrm) {
  int q = blockIdx.x * 256 + threadIdx.x;
  float row[16];
  const float4* xv = (const float4*)(x + (size_t)q * D_);
  float4 a = xv[0], b = xv[1], c = xv[2], d = xv[3];
  row[0]=a.x; row[1]=a.y; row[2]=a.z; row[3]=a.w;
  row[4]=b.x; row[5]=b.y; row[6]=b.z; row[7]=b.w;
  row[8]=c.x; row[9]=c.y; row[10]=c.z; row[11]=c.w;
  row[12]=d.x; row[13]=d.y; row[14]=d.z; row[15]=d.w;
  nrm[q] = np_norm16(row);
}

// ascending insert; '>' keeps earlier (lower idx) on ties
__device__ __forceinline__ void insert16(float d, int j, float (&kd)[K_], int (&ki)[K_]) {
  float cd = d; int ci = j;
#pragma unroll
  for (int p = 0; p < K_; ++p) {
    bool gt = kd[p] > cd;
    float t0 = gt ? cd : kd[p];
    float t1 = gt ? kd[p] : cd;
    int   t2 = gt ? ci : ki[p];
    int   t3 = gt ? ki[p] : ci;
    kd[p] = t0; cd = t1; ki[p] = t2; ci = t3;
  }
}

__device__ __forceinline__ void flushbuf(u64* __restrict__ pbuf, int tid,
                                         int& count, float& thr,
                                         float (&kd)[K_], int (&ki)[K_]) {
#pragma unroll 1
  for (int s = 0; s < CAP_; ++s) {
    if (s < count) {
      u64 e = pbuf[(size_t)s * BT_ + tid];
      float d = __uint_as_float((unsigned)(e >> 32));
      if (d < thr) {
        int j = (int)(e & 0xffffu);
        insert16(d, j, kd, ki);
        thr = kd[K_ - 1];
      }
    }
  }
  count = 0;
}

__global__ __launch_bounds__(BT_, 2) void knn_fused(const float* __restrict__ x,
                                                    const float* __restrict__ nrm,
                                                    int* __restrict__ out) {
  __shared__ u64 smem[8192];                       // 64 KB
  float4* stageR = (float4*)smem;                  // [(w*2+b)*32 + i], 8 KB
  float*  stageN = (float*)(smem + 1024);          // [(w*2+b)*8 + i], 512 B
  u64*    pbuf   = smem + 1088;                    // [s*512 + tid], 48 KB
  // merge overlay (after __syncthreads): smem[(seg*16+p)*64 + qlocal], 64 KB

  const int tid  = threadIdx.x;
  const int w    = tid >> 6;                       // wave id = segment
  const int lane = tid & 63;                       // query-local id
  const int q    = blockIdx.x * 64 + lane;         // global query
  const int bq   = (int)((blockIdx.x * 64u) >> 13);  // batch (block-uniform)
  const int row0 = bq * N_ + w * SEG_;
  const float* __restrict__ cbase = x + (size_t)row0 * D_;
  const float* __restrict__ nbase = nrm + row0;

  float qa[D_];
  {
    const float4* qv = (const float4*)(x + (size_t)q * D_);
    float4 v0 = qv[0], v1 = qv[1], v2 = qv[2], v3 = qv[3];
    qa[0]=v0.x; qa[1]=v0.y; qa[2]=v0.z; qa[3]=v0.w;
    qa[4]=v1.x; qa[5]=v1.y; qa[6]=v1.z; qa[7]=v1.w;
    qa[8]=v2.x; qa[9]=v2.y; qa[10]=v2.z; qa[11]=v2.w;
    qa[12]=v3.x; qa[13]=v3.y; qa[14]=v3.z; qa[15]=v3.w;
  }
  const float ni = nrm[q];

  float kd[K_]; int ki[K_];
#pragma unroll
  for (int p = 0; p < K_; ++p) { kd[p] = 3.4e38f; ki[p] = 0; }
  float thr = 3.4e38f;
  int count = 0;

  // stage chunk 0 (per-wave-private LDS; wave-synchronous, no barrier)
  {
    const float4* gs = (const float4*)cbase;
    if (lane < 32) stageR[(w * 2 + 0) * 32 + lane] = gs[lane];
    if (lane < CH_) stageN[(w * 2 + 0) * CH_ + lane] = nbase[lane];
  }

#pragma unroll 1
  for (int c = 0; c < NCH_; ++c) {
    const int b = c & 1;
    // prefetch chunk c+1 into registers (overlaps compute below)
    float4 p0; float pn = 0.f;
    const bool more = (c + 1 < NCH_);
    if (more) {
      const float4* gs = (const float4*)(cbase + (size_t)(c + 1) * CH_ * D_);
      if (lane < 32) p0 = gs[lane];
      if (lane < CH_) pn = nbase[(c + 1) * CH_ + lane];
    }

    const float4* rows = stageR + (w * 2 + b) * 32;
    const float*  nn   = stageN + (w * 2 + b) * CH_;

#pragma unroll 1
    for (int t = 0; t < CH_; t += 2) {
      float4 r00 = rows[t*4+0], r01 = rows[t*4+1], r02 = rows[t*4+2], r03 = rows[t*4+3];
      float4 r10 = rows[t*4+4], r11 = rows[t*4+5], r12 = rows[t*4+6], r13 = rows[t*4+7];
      float nj0 = nn[t], nj1 = nn[t + 1];

      float c0[16] = {r00.x,r00.y,r00.z,r00.w, r01.x,r01.y,r01.z,r01.w,
                      r02.x,r02.y,r02.z,r02.w, r03.x,r03.y,r03.z,r03.w};
      float c1[16] = {r10.x,r10.y,r10.z,r10.w, r11.x,r11.y,r11.z,r11.w,
                      r12.x,r12.y,r12.z,r12.w, r13.x,r13.y,r13.z,r13.w};

      // two independent np-exact FMA chains (k ascending, single accumulator)
      float dot0 = 0.f, dot1 = 0.f;
#pragma unroll
      for (int d = 0; d < D_; ++d) {
        dot0 = __builtin_fmaf(qa[d], c0[d], dot0);
        dot1 = __builtin_fmaf(qa[d], c1[d], dot1);
      }
      float d0, d1;
      {
#pragma clang fp contract(off)
        float i0 = -2.0f * dot0;  float i1 = -2.0f * dot1;
        float u0 = ni + i0;       float u1 = ni + i1;
        d0 = u0 + nj0;            d1 = u1 + nj1;
      }

      if (d0 < thr) {
        pbuf[(size_t)count * BT_ + tid] =
            ((u64)__float_as_uint(d0) << 32) | (unsigned)(c * CH_ + t);
        ++count;
      }
      if (d1 < thr) {
        pbuf[(size_t)count * BT_ + tid] =
            ((u64)__float_as_uint(d1) << 32) | (unsigned)(c * CH_ + t + 1);
        ++count;
      }
      if (__any(count >= CAP_ - 1)) flushbuf(pbuf, tid, count, thr, kd, ki);
    }

    // write prefetched chunk into the other buffer
    if (more) {
      if (lane < 32) stageR[(w * 2 + (b ^ 1)) * 32 + lane] = p0;
      if (lane < CH_) stageN[(w * 2 + (b ^ 1)) * CH_ + lane] = pn;
    }
  }
  flushbuf(pbuf, tid, count, thr, kd, ki);

  // ---- publish sorted per-segment top-16 as packed u64, then 8-way merge ----
  __syncthreads();   // all waves done with stage/push regions before overlay
#pragma unroll
  for (int p = 0; p < K_; ++p) {
    smem[((size_t)w * 16 + p) * 64 + lane] =
        ((u64)mono32(kd[p]) << 32) | (unsigned)(w * SEG_ + ki[p]);
  }
  __syncthreads();

  // merge: 8 lanes per query; wave w handles queries [w*8, w*8+8).
  {
    const int qi = w * 8 + (lane >> 3);            // block-local query
    const int s  = lane & 7;                       // my segment stream
    const int gq = blockIdx.x * 64 + qi;           // global query
    int ptr = 0;
#pragma unroll 1
    for (int r = 0; r < K_; ++r) {
      u64 h = smem[((size_t)s * 16 + ptr) * 64 + qi];
      u64 m = h, o;
      o = __shfl_xor(m, 1); m = (o < m) ? o : m;
      o = __shfl_xor(m, 2); m = (o < m) ? o : m;
      o = __shfl_xor(m, 4); m = (o < m) ? o : m;
      if (h == m) ++ptr;                           // exactly one lane advances
      if (s == 0) out[(size_t)gq * K_ + r] = (int)(m & 0xffffu);
    }
  }
}

extern "C" void kernel_launch(void* const* d_in, const int* in_sizes, int n_in,
                              void* d_out, int out_size, void* d_ws, size_t ws_size,
                              hipStream_t stream) {
  const float* x = (const float*)d_in[0];
  float* nrm = (float*)d_ws;                       // 128 KB of workspace
  int* out = (int*)d_out;

  knn_norms<<<NQ_ / 256, 256, 0, stream>>>(x, nrm);
  knn_fused<<<NQ_ / 64, BT_, 0, stream>>>(x, nrm, out);
}